// Round 8
// baseline (123.721 us; speedup 1.0000x reference)
//
#include <hip/hip_runtime.h>

#define NT 512
#define TM 32
#define NBLK (65536/TM)

typedef unsigned int u32;
typedef unsigned short u16;
typedef __attribute__((ext_vector_type(4))) float f32x4;
typedef __attribute__((ext_vector_type(8))) _Float16 f16x8;
typedef __attribute__((ext_vector_type(4))) _Float16 f16x4;

namespace {
constexpr int TI_[28] = {0,1,1,2,2,2,3,3,3,3,4,4,4,4,4,5,5,5,5,5,5,6,6,6,6,6,6,6};
constexpr int TJ_[28] = {0,0,1,0,1,2,0,1,2,3,0,1,2,3,4,0,1,2,3,4,5,0,1,2,3,4,5,6};
constexpr bool DG_[28] = {1,0,1,0,0,1,0,0,0,1,0,0,0,0,1,0,0,0,0,0,1,0,0,0,0,0,0,1};

// 19 weight images in ws, byte offsets. Per image: [hi plane][lo plane],
// each plane = [K/8 slots][N][8 f16].  (unchanged)
constexpr int IB[20] = {0,16384,81920,147456,163840,180224,245760,311296,319488,
                        335872,401408,466944,475136,540672,606208,614400,630784,
                        696320,761856,778240};
constexpr int IN_[19]  = {128,128,128,32,128,128,128,16,128,128,128,16,128,128,16,128,128,128,32};
constexpr int ITY_[19] = {0,1,1,2,3,4,4,5,0,1,1,6,4,4,5,0,1,1,2};
constexpr int TOTF16 = 778240/2;
}

__device__ __forceinline__ float sp_f(float z) {
  float t = exp2f(-fabsf(z)*1.44269504f);
  return fmaxf(z, 0.f) + 0.69314718f*__log2f(1.f + t);
}
__device__ __forceinline__ float sigm_f(float z) {
  float t = exp2f(-z*1.44269504f);
  return __builtin_amdgcn_rcpf(1.f + t);
}
__device__ __forceinline__ float sig_a(float a) {  // sigmoid(z) from a=softplus(z)
  return 1.f - exp2f(-a*1.44269504f);
}

__device__ __forceinline__ u16 h2b(_Float16 h) { union{_Float16 f; u16 u;} c; c.f = h; return c.u; }
__device__ __forceinline__ u16 f16b(float x)   { return h2b((_Float16)x); }
__device__ __forceinline__ float b2f(u16 b)    { union{u16 u; _Float16 f;} c; c.u = b; return (float)c.f; }
__device__ __forceinline__ f16x8 fz8()         { return (f16x8)(_Float16)0.f; }

__device__ __forceinline__ f32x4 mm(f16x8 a, f16x8 b, f32x4 c) {
  return __builtin_amdgcn_mfma_f32_16x16x32_f16(a, b, c, 0, 0, 0);
}

// ---- f16 plane [32 m][128 n], 16 slots/row of 16B, slot XOR (row&7) ----
__device__ __forceinline__ f16x8 aread(const u16* P, int row, int s) {
  return *(const f16x8*)(P + row*128 + ((s ^ (row & 7)) << 3));
}
__device__ __forceinline__ int aidx4(int mrow, int n2) {
  return mrow*128 + (((n2 >> 3) ^ (mrow & 7)) << 3) + (n2 & 7);
}
__device__ __forceinline__ void awrite4(u16* P, int mrow, int n2, f16x4 v) {
  *(f16x4*)(P + aidx4(mrow, n2)) = v;
}
__device__ __forceinline__ f16x4 aread4(const u16* P, int mrow, int n2) {
  return *(const f16x4*)(P + aidx4(mrow, n2));
}
// ---- [32][8] q-matrix plane: only k-group 0 real, others zero ----
__device__ __forceinline__ f16x8 aq8(const u16* P, int row, int g) {
  f16x8 v = *(const f16x8*)(P + row*8);
  return g ? fz8() : v;
}
// ---- [32][32] ub plane: 4 slots, XOR (row&3) ----
__device__ __forceinline__ f16x8 ubread(const u16* P, int row, int g) {
  return *(const f16x8*)(P + row*32 + ((g ^ (row & 3)) << 3));
}
// ---- weight fragment (A operand) from global image plane ----
__device__ __forceinline__ f16x8 bread(const char* img, int N, int sk, int n) {
  return *(const f16x8*)(img + ((sk*N + n) << 4));
}

struct __align__(16) Smem {
  u16 mh1[4096], mh2[4096], mh3[4096];   // mass/pot act hi (sigma sources, reused)
  u16 X[4096], Y[4096];                  // lo ping-pong / grad / jvp / fric ping-pong
  u16 qmh[256], qml[256], qdb[256];      // [32][8]
  u16 ub[1024];                          // [32][32] cotangent (swizzled)
  float cTm[896];                        // c then vals, plain [28][32]
  u16 dcH[896], cfH[896];                // [28][32] plain f16
  float GQ1[256], GQp[256];              // [32][8]
  float V[32];
};
static_assert(sizeof(Smem) <= 54613, "need 3 blocks/CU");

// ---------- fwd hi/lo: D = W^T X^T, TC n2-tiles {tile0 + j*tstep} ----------
template<int KS, bool QSRC, int TC>
__device__ __forceinline__ void fwd_hl(const u16* Bh, const u16* Bl, u16* Oh, u16* Ol,
                                       const char* img, int hb, const float* bias,
                                       int tile0, int tstep, int l) {
  const int m = l & 15, g = l >> 4;
  f32x4 H[TC][2], X[TC][2];
  #pragma unroll
  for (int j=0;j<TC;++j)
    #pragma unroll
    for (int mt=0;mt<2;++mt) { H[j][mt]=(f32x4){0,0,0,0}; X[j][mt]=(f32x4){0,0,0,0}; }
  #pragma unroll
  for (int ks=0; ks<KS; ++ks) {
    const int sk = ks*4 + g;
    f16x8 bh[2], bl[2];
    #pragma unroll
    for (int mt=0;mt<2;++mt) {
      const int row = mt*16+m;
      bh[mt] = QSRC ? aq8(Bh,row,g) : aread(Bh,row,sk);
      bl[mt] = QSRC ? aq8(Bl,row,g) : aread(Bl,row,sk);
    }
    #pragma unroll
    for (int j=0;j<TC;++j) {
      const int n = (tile0 + j*tstep)*16 + m;
      const f16x8 wh = bread(img,128,sk,n);
      const f16x8 wl = bread(img+hb,128,sk,n);
      #pragma unroll
      for (int mt=0;mt<2;++mt) {
        H[j][mt]=mm(wh,bh[mt],H[j][mt]);
        X[j][mt]=mm(wl,bh[mt],X[j][mt]);
        X[j][mt]=mm(wh,bl[mt],X[j][mt]);
      }
    }
  }
  #pragma unroll
  for (int j=0;j<TC;++j) {
    const int n2 = (tile0 + j*tstep)*16 + 4*g;
    f32x4 bv = bias ? *(const f32x4*)(bias + n2) : (f32x4){0,0,0,0};
    #pragma unroll
    for (int mt=0;mt<2;++mt) {
      const int mrow = mt*16 + m;
      f16x4 vh, vl;
      #pragma unroll
      for (int r=0;r<4;++r) {
        const float o = sp_f(H[j][mt][r] + X[j][mt][r]*(1.f/4096.f) + bv[r]);
        const _Float16 hh = (_Float16)o;
        vh[r] = hh;
        vl[r] = (_Float16)((o - (float)hh)*4096.f);
      }
      awrite4(Oh, mrow, n2, vh);
      awrite4(Ol, mrow, n2, vl);
    }
  }
}

// ---------- fwd hi-only: TC n2-tiles ----------
template<int KS, bool QSRC, int TC>
__device__ __forceinline__ void fwd_h(const u16* Bh, u16* Oh, const char* img,
                                      const float* bias, int tile0, int tstep, int l) {
  const int m = l & 15, g = l >> 4;
  f32x4 H[TC][2];
  #pragma unroll
  for (int j=0;j<TC;++j)
    #pragma unroll
    for (int mt=0;mt<2;++mt) H[j][mt]=(f32x4){0,0,0,0};
  #pragma unroll
  for (int ks=0; ks<KS; ++ks) {
    const int sk = ks*4 + g;
    f16x8 bh[2];
    #pragma unroll
    for (int mt=0;mt<2;++mt) {
      const int row = mt*16+m;
      bh[mt] = QSRC ? aq8(Bh,row,g) : aread(Bh,row,sk);
    }
    #pragma unroll
    for (int j=0;j<TC;++j) {
      const f16x8 wh = bread(img,128,sk,(tile0 + j*tstep)*16+m);
      #pragma unroll
      for (int mt=0;mt<2;++mt) H[j][mt]=mm(wh,bh[mt],H[j][mt]);
    }
  }
  #pragma unroll
  for (int j=0;j<TC;++j) {
    const int n2 = (tile0 + j*tstep)*16 + 4*g;
    f32x4 bv = bias ? *(const f32x4*)(bias + n2) : (f32x4){0,0,0,0};
    #pragma unroll
    for (int mt=0;mt<2;++mt) {
      const int mrow = mt*16 + m;
      f16x4 vh;
      #pragma unroll
      for (int r=0;r<4;++r) vh[r] = (_Float16)sp_f(H[j][mt][r] + bv[r]);
      awrite4(Oh, mrow, n2, vh);
    }
  }
}

// ---------- grad K=128: out = sig_a(Sig) .* (W^T X^T) ----------
template<int TC>
__device__ __forceinline__ void grad128(const u16* Bin, const u16* Sig, u16* Out,
                                        const char* img, int tile0, int tstep, int l) {
  const int m = l & 15, g = l >> 4;
  f32x4 acc[TC][2];
  #pragma unroll
  for (int j=0;j<TC;++j)
    #pragma unroll
    for (int mt=0;mt<2;++mt) acc[j][mt]=(f32x4){0,0,0,0};
  #pragma unroll
  for (int ks=0; ks<4; ++ks) {
    const int sk = ks*4 + g;
    f16x8 bh[2];
    #pragma unroll
    for (int mt=0;mt<2;++mt) bh[mt] = aread(Bin, mt*16+m, sk);
    #pragma unroll
    for (int j=0;j<TC;++j) {
      const f16x8 wh = bread(img,128,sk,(tile0 + j*tstep)*16+m);
      #pragma unroll
      for (int mt=0;mt<2;++mt) acc[j][mt]=mm(wh,bh[mt],acc[j][mt]);
    }
  }
  #pragma unroll
  for (int j=0;j<TC;++j) {
    const int n2 = (tile0 + j*tstep)*16 + 4*g;
    #pragma unroll
    for (int mt=0;mt<2;++mt) {
      const int mrow = mt*16 + m;
      const f16x4 sg = aread4(Sig, mrow, n2);
      f16x4 o;
      #pragma unroll
      for (int r=0;r<4;++r) o[r] = (_Float16)(sig_a((float)sg[r]) * acc[j][mt][r]);
      awrite4(Out, mrow, n2, o);
    }
  }
}

// ---------- grad K=32: B from ub (ASRC=0) or q8 (ASRC=1) ----------
template<int ASRC, int TC>
__device__ __forceinline__ void grad32(const u16* Bin, const u16* Sig, u16* Out,
                                       const char* img, int tile0, int tstep, int l) {
  const int m = l & 15, g = l >> 4;
  f32x4 acc[TC][2];
  #pragma unroll
  for (int j=0;j<TC;++j)
    #pragma unroll
    for (int mt=0;mt<2;++mt) acc[j][mt]=(f32x4){0,0,0,0};
  {
    f16x8 bh[2];
    #pragma unroll
    for (int mt=0;mt<2;++mt) {
      const int row = mt*16+m;
      bh[mt] = (ASRC==0) ? ubread(Bin,row,g) : aq8(Bin,row,g);
    }
    #pragma unroll
    for (int j=0;j<TC;++j) {
      const f16x8 wh = bread(img,128,g,(tile0 + j*tstep)*16+m);
      #pragma unroll
      for (int mt=0;mt<2;++mt) acc[j][mt]=mm(wh,bh[mt],acc[j][mt]);
    }
  }
  #pragma unroll
  for (int j=0;j<TC;++j) {
    const int n2 = (tile0 + j*tstep)*16 + 4*g;
    #pragma unroll
    for (int mt=0;mt<2;++mt) {
      const int mrow = mt*16 + m;
      const f16x4 sg = aread4(Sig, mrow, n2);
      f16x4 o;
      #pragma unroll
      for (int r=0;r<4;++r) o[r] = (_Float16)(sig_a((float)sg[r]) * acc[j][mt][r]);
      awrite4(Out, mrow, n2, o);
    }
  }
}

// ---------- G2p: B = up[m]*sigma(a3p) on the fly; image pre-scaled by W3p ----------
template<int TC>
__device__ __forceinline__ void gradPotF(const u16* A3p, const float* V, float pb3v,
                                         const u16* Sig, u16* Out, const char* img,
                                         int tile0, int tstep, int l) {
  const int m = l & 15, g = l >> 4;
  float up[2];
  #pragma unroll
  for (int mt=0;mt<2;++mt) up[mt] = sigm_f(V[mt*16+m] + pb3v);
  f32x4 acc[TC][2];
  #pragma unroll
  for (int j=0;j<TC;++j)
    #pragma unroll
    for (int mt=0;mt<2;++mt) acc[j][mt]=(f32x4){0,0,0,0};
  #pragma unroll
  for (int ks=0; ks<4; ++ks) {
    const int sk = ks*4 + g;
    f16x8 bh[2];
    #pragma unroll
    for (int mt=0;mt<2;++mt) {
      const f16x8 a3 = aread(A3p, mt*16+m, sk);
      f16x8 t;
      #pragma unroll
      for (int e=0;e<8;++e) t[e] = (_Float16)(up[mt]*sig_a((float)a3[e]));
      bh[mt] = t;
    }
    #pragma unroll
    for (int j=0;j<TC;++j) {
      const f16x8 wh = bread(img,128,sk,(tile0 + j*tstep)*16+m);
      #pragma unroll
      for (int mt=0;mt<2;++mt) acc[j][mt]=mm(wh,bh[mt],acc[j][mt]);
    }
  }
  #pragma unroll
  for (int j=0;j<TC;++j) {
    const int n2 = (tile0 + j*tstep)*16 + 4*g;
    #pragma unroll
    for (int mt=0;mt<2;++mt) {
      const int mrow = mt*16 + m;
      const f16x4 sg = aread4(Sig, mrow, n2);
      f16x4 o;
      #pragma unroll
      for (int r=0;r<4;++r) o[r] = (_Float16)(sig_a((float)sg[r]) * acc[j][mt][r]);
      awrite4(Out, mrow, n2, o);
    }
  }
}

// ---------- l3 (28 outputs): 4 waves wg 0-3: n2t = wg&1, mt = wg>>1 ----------
template<bool HL>
__device__ __forceinline__ void l3(const u16* Bh, const u16* Bl, const char* img, int hb,
                                   const float* b3, float* cT, u16* cH, int wg, int l) {
  const int m = l & 15, g = l >> 4;
  const int n2t = wg & 1, mt = wg >> 1;
  const int mrow = mt*16 + m;
  f32x4 H = {0,0,0,0}, X = {0,0,0,0};
  #pragma unroll
  for (int ks=0; ks<4; ++ks) {
    const int sk = ks*4 + g;
    const f16x8 bh = aread(Bh, mrow, sk);
    const f16x8 wh = bread(img,32,sk, n2t*16+m);
    H = mm(wh, bh, H);
    if (HL) {
      const f16x8 wl = bread(img+hb,32,sk, n2t*16+m);
      const f16x8 bl = aread(Bl, mrow, sk);
      X = mm(wl, bh, X);
      X = mm(wh, bl, X);
    }
  }
  const int u0 = n2t*16 + 4*g;
  if (u0 < 28) {
    f32x4 bv = b3 ? *(const f32x4*)(b3 + u0) : (f32x4){0,0,0,0};
    #pragma unroll
    for (int r=0;r<4;++r) {
      const float v = H[r] + (HL ? X[r]*(1.f/4096.f) : 0.f) + bv[r];
      if (HL) cT[(u0+r)*32 + mrow] = v;
      else    cH[(u0+r)*32 + mrow] = f16b(v);
    }
  }
}

// ---------- n16: head (-> V) or gq (-> GQ[32][8]); 2 waves mt 0-1 ----------
template<bool HEAD>
__device__ __forceinline__ void n16(const u16* Bin, const char* img,
                                    float* GQ, float* V, int mt, int l) {
  const int m = l & 15, g = l >> 4;
  const int mrow = mt*16 + m;
  f32x4 acc = {0,0,0,0};
  #pragma unroll
  for (int ks=0; ks<4; ++ks) {
    const int sk = ks*4 + g;
    const f16x8 bh = aread(Bin, mrow, sk);
    const f16x8 wh = bread(img,16,sk,m);
    acc = mm(wh, bh, acc);
  }
  if (HEAD) {
    if (g == 0) V[mrow] = acc[0];
  } else {
    if (g < 2) {
      #pragma unroll
      for (int r=0;r<4;++r) GQ[mrow*8 + 4*g + r] = acc[r];
    }
  }
}

// ================= pack kernel (unchanged) =================
__global__ __launch_bounds__(256)
void pack_kernel(const float* __restrict__ mW0, const float* __restrict__ mb0,
                 const float* __restrict__ mW1, const float* __restrict__ mW2,
                 const float* __restrict__ mW3,
                 const float* __restrict__ pW0, const float* __restrict__ pb0,
                 const float* __restrict__ pW1, const float* __restrict__ pW2,
                 const float* __restrict__ pW3,
                 const float* __restrict__ fW0, const float* __restrict__ fb0,
                 const float* __restrict__ fW1, const float* __restrict__ fW2,
                 const float* __restrict__ fW3,
                 u16* __restrict__ ws)
{
  const int idx = blockIdx.x*256 + threadIdx.x;
  if (idx >= TOTF16) return;
  int img = 0;
  #pragma unroll
  for (int i = 1; i < 19; ++i) if (idx >= IB[i]/2) img = i;
  const int rem = idx - IB[img]/2;
  const int N = IN_[img];
  const int psz = (IB[img+1] - IB[img]) / 4;   // f16 per plane = K*N
  const int plane = rem >= psz;
  const int e = plane ? rem - psz : rem;
  const int slot = e / (N*8);
  const int r1 = e - slot*(N*8);
  const int n = r1 >> 3, ee = r1 & 7;
  const int k = slot*8 + ee;

  const float* W = nullptr; const float* B = nullptr;
  switch (img) {
    case 0:  W = mW0; B = mb0; break;
    case 1:  W = mW1; break;   case 2:  W = mW2; break;
    case 3:  W = mW3; break;   case 4:  W = mW3; break;
    case 5:  W = mW2; break;   case 6:  W = mW1; break;
    case 7:  W = mW0; break;
    case 8:  W = pW0; B = pb0; break;
    case 9:  W = pW1; break;   case 10: W = pW2; break;
    case 11: W = pW3; break;   case 12: W = pW2; break;
    case 13: W = pW1; break;   case 14: W = pW0; break;
    case 15: W = fW0; B = fb0; break;
    case 16: W = fW1; break;   case 17: W = fW2; break;
    default: W = fW3; break;
  }
  float v = 0.f;
  switch (ITY_[img]) {
    case 0: v = (k < 7) ? W[k*128 + n] : (k == 7 ? B[n] : 0.f); break;
    case 1: v = W[k*128 + n]; break;
    case 2: v = (n < 28) ? W[k*28 + n] : 0.f; break;
    case 3: v = (k < 28) ? W[n*28 + k] : 0.f; break;
    case 4: v = W[n*128 + k]; break;
    case 5: v = (n < 7) ? W[n*128 + k] : 0.f; break;
    default: v = (n == 0) ? W[k] : 0.f; break;
  }
  if (img == 12) v *= pW3[k];   // fold diag(W3p) into G2p's image
  const _Float16 h = (_Float16)v;
  union { _Float16 f; u16 u; } c;
  c.f = plane ? (_Float16)((v - (float)h) * 4096.f) : h;
  ws[idx] = c.u;
}

// ================= main kernel =================
__global__ __launch_bounds__(NT, 6)
void delan_kernel(const float* __restrict__ qg, const float* __restrict__ qdg,
    const float* __restrict__ mb1, const float* __restrict__ mb2, const float* __restrict__ mb3,
    const float* __restrict__ pb1, const float* __restrict__ pb2, const float* __restrict__ pb3,
    const float* __restrict__ fb1, const float* __restrict__ fb2, const float* __restrict__ fb3,
    const char* __restrict__ ws, float* __restrict__ out)
{
  __shared__ Smem S;
  const int t = threadIdx.x;
  const int l = t & 63;
  const int w = __builtin_amdgcn_readfirstlane(t >> 6);
  const int wg = w & 3;
  const int s0 = blockIdx.x * TM;

  // ---- ph0: build q / qd matrices ----
  if (t < 256) {
    const int m = t >> 3, c = t & 7;
    const float v = (c < 7) ? qg[(s0 + m)*7 + c] : 1.f;   // col 7 = 1.0 bias hook
    const _Float16 hh = (_Float16)v;
    S.qmh[t] = h2b(hh);
    S.qml[t] = f16b((v - (float)hh)*4096.f);
  } else {
    const int idx = t - 256;
    const int m = idx >> 3, c = idx & 7;
    S.qdb[idx] = (c < 7) ? f16b(qdg[(s0 + m)*7 + c]) : (u16)0;
  }
  __syncthreads();

  // ph1: L0m -> mh1 + X(lo1)
  fwd_hl<1,true,1>(S.qmh, S.qml, S.mh1, S.X, ws+IB[0], (IB[1]-IB[0])/2, nullptr, w, 1, l);
  __syncthreads();
  // ph2: L1m -> mh2 + Y(lo2)
  fwd_hl<4,false,1>(S.mh1, S.X, S.mh2, S.Y, ws+IB[1], (IB[2]-IB[1])/2, mb1, w, 1, l);
  __syncthreads();
  // ph3: L2m -> mh3 + X(lo3)
  fwd_hl<4,false,1>(S.mh2, S.Y, S.mh3, S.X, ws+IB[2], (IB[3]-IB[2])/2, mb2, w, 1, l);
  __syncthreads();
  // ph4: l3m (w0-3) | d1 -> Y (w4-7)
  if (w < 4) l3<true>(S.mh3, S.X, ws+IB[3], (IB[4]-IB[3])/2, mb3, S.cTm, nullptr, wg, l);
  else       grad32<1,2>(S.qdb, S.mh1, S.Y, ws+IB[0], wg, 4, l);
  __syncthreads();
  // ph5: P1 (w0) | d2: Y -> X (w4-7)
  if (w == 0 && l < 32) {
    const int ml = l;
    float qdv[7];
    #pragma unroll
    for (int i = 0; i < 7; ++i) qdv[i] = qdg[(s0 + ml)*7 + i];
    float vals[28], wvv[7] = {0,0,0,0,0,0,0};
    #pragma unroll
    for (int u = 0; u < 28; ++u) {
      const float cv = S.cTm[u*32 + ml];
      vals[u] = DG_[u] ? __expf(cv) : cv;
    }
    #pragma unroll
    for (int u = 0; u < 28; ++u) wvv[TJ_[u]] = fmaf(vals[u], qdv[TI_[u]], wvv[TJ_[u]]);
    #pragma unroll
    for (int u = 0; u < 28; ++u) S.cTm[u*32 + ml] = vals[u];   // c -> vals in place
    #pragma unroll
    for (int u = 0; u < 28; ++u) {
      const float uval = (DG_[u] ? vals[u] : 1.f) * qdv[TI_[u]] * wvv[TJ_[u]];
      S.ub[ml*32 + (((u >> 3) ^ (ml & 3)) << 3) + (u & 7)] = f16b(uval);
    }
    #pragma unroll
    for (int u = 28; u < 32; ++u)
      S.ub[ml*32 + (((u >> 3) ^ (ml & 3)) << 3) + (u & 7)] = 0;
  } else if (w >= 4) {
    grad128<2>(S.Y, S.mh2, S.X, ws+IB[1], wg, 4, l);
  }
  __syncthreads();
  // ph6: d3: X -> Y (8 waves)
  grad128<1>(S.X, S.mh3, S.Y, ws+IB[2], w, 1, l);
  __syncthreads();
  // ph7: dc = l3(Y) (w0-3) | G3: ub -> X (w4-7)
  if (w < 4) l3<false>(S.Y, nullptr, ws+IB[3], 0, nullptr, nullptr, S.dcH, wg, l);
  else       grad32<0,2>(S.ub, S.mh3, S.X, ws+IB[4], wg, 4, l);
  __syncthreads();
  // ph8: G2: X -> Y (8 waves)
  grad128<1>(S.X, S.mh2, S.Y, ws+IB[5], w, 1, l);
  __syncthreads();
  // ph9: G1: Y -> X (8 waves)
  grad128<1>(S.Y, S.mh1, S.X, ws+IB[6], w, 1, l);
  __syncthreads();
  // ph10: gq = n16(X) (w0-1) | L0p -> mh1 (w4-7)
  if (w < 2)       n16<false>(S.X, ws+IB[7], S.GQ1, nullptr, w, l);
  else if (w >= 4) fwd_h<1,true,2>(S.qmh, S.mh1, ws+IB[8], nullptr, wg, 4, l);
  __syncthreads();
  // ph11: L1p: mh1 -> mh2 (w0-3) | L0f -> Y (w4-7)
  if (w < 4) fwd_h<4,false,2>(S.mh1, S.mh2, ws+IB[9], pb1, wg, 4, l);
  else       fwd_h<1,true,2>(S.qmh, S.Y, ws+IB[15], nullptr, wg, 4, l);
  __syncthreads();
  // ph12: L2p: mh2 -> mh3 (w0-3) | L1f: Y -> X (w4-7)
  if (w < 4) fwd_h<4,false,2>(S.mh2, S.mh3, ws+IB[10], pb2, wg, 4, l);
  else       fwd_h<4,false,2>(S.Y, S.X, ws+IB[16], fb1, wg, 4, l);
  __syncthreads();
  // ph13: head = n16(mh3) (w0-1) | L2f: X -> Y (w4-7)
  if (w < 2)       n16<true>(S.mh3, ws+IB[11], nullptr, S.V, w, l);
  else if (w >= 4) fwd_h<4,false,2>(S.X, S.Y, ws+IB[17], fb2, wg, 4, l);
  __syncthreads();
  // ph14: G2p in-place mh2 (w0-3) | l3f(Y) -> cfH (w4-7)
  if (w < 4) gradPotF<2>(S.mh3, S.V, pb3[0], S.mh2, S.mh2, ws+IB[12], wg, 4, l);
  else       l3<false>(S.Y, nullptr, ws+IB[18], 0, fb3, nullptr, S.cfH, wg, l);
  __syncthreads();
  // ph15: G1p: mh2 -> X (8 waves)
  grad128<1>(S.mh2, S.mh1, S.X, ws+IB[13], w, 1, l);
  __syncthreads();
  // ph16: gqp = n16(X) (w0-1)
  if (w < 2) n16<false>(S.X, ws+IB[14], S.GQp, nullptr, w, l);
  __syncthreads();

  // ph17: P2 + P3 (wave 0, lanes 0-31)
  if (w == 0 && l < 32) {
    const int ml = l;
    float qdv[7];
    #pragma unroll
    for (int i = 0; i < 7; ++i) qdv[i] = qdg[(s0 + ml)*7 + i];
    float lv[28];
    #pragma unroll
    for (int u = 0; u < 28; ++u) lv[u] = S.cTm[u*32 + ml];
    float wvv[7] = {0,0,0,0,0,0,0};
    #pragma unroll
    for (int u = 0; u < 28; ++u) wvv[TJ_[u]] = fmaf(lv[u], qdv[TI_[u]], wvv[TJ_[u]]);
    float cor[7] = {0,0,0,0,0,0,0}, t2[7] = {0,0,0,0,0,0,0};
    #pragma unroll
    for (int u = 0; u < 28; ++u) {
      const float dv = (DG_[u] ? lv[u] : 1.f) * b2f(S.dcH[u*32 + ml]);
      cor[TI_[u]] = fmaf(dv, wvv[TJ_[u]], cor[TI_[u]]);
      t2[TJ_[u]]  = fmaf(dv, qdv[TI_[u]], t2[TJ_[u]]);
    }
    #pragma unroll
    for (int u = 0; u < 28; ++u) cor[TI_[u]] = fmaf(lv[u], t2[TJ_[u]], cor[TI_[u]]);
    float r7[7];
    #pragma unroll
    for (int i = 0; i < 7; ++i)
      r7[i] = S.GQ1[ml*8 + i] - cor[i] - S.GQp[ml*8 + i] - 1e-3f*qdv[i];
    // friction
    float fv[28];
    #pragma unroll
    for (int u = 0; u < 28; ++u) {
      const float cv = b2f(S.cfH[u*32 + ml]);
      fv[u] = DG_[u] ? __expf(cv) : cv;
    }
    float wf[7] = {0,0,0,0,0,0,0};
    #pragma unroll
    for (int u = 0; u < 28; ++u) wf[TJ_[u]] = fmaf(fv[u], qdv[TI_[u]], wf[TJ_[u]]);
    #pragma unroll
    for (int u = 0; u < 28; ++u) r7[TI_[u]] -= fv[u]*wf[TJ_[u]];

    float L[7][7];
    #pragma unroll
    for (int i = 0; i < 7; ++i)
      #pragma unroll
      for (int j = 0; j < 7; ++j) L[i][j] = 0.f;
    #pragma unroll
    for (int u = 0; u < 28; ++u) L[TI_[u]][TJ_[u]] = lv[u];

    float M[7][7];
    #pragma unroll
    for (int i = 0; i < 7; ++i)
      #pragma unroll
      for (int j = 0; j < 7; ++j)
        if (j <= i) {
          float sum = (i == j) ? 1.1e-3f : 0.f;
          #pragma unroll
          for (int k = 0; k < 7; ++k) if (k <= j) sum = fmaf(L[i][k], L[j][k], sum);
          M[i][j] = sum;
        }
    float C[7][7];
    #pragma unroll
    for (int i = 0; i < 7; ++i)
      #pragma unroll
      for (int j = 0; j < 7; ++j)
        if (j <= i) {
          float sum = M[i][j];
          #pragma unroll
          for (int k = 0; k < 7; ++k) if (k < j) sum -= C[i][k] * C[j][k];
          if (j == i) C[i][j] = sqrtf(fmaxf(sum, 1e-12f));
          else        C[i][j] = sum / C[j][j];
        }
    float y[7];
    #pragma unroll
    for (int i = 0; i < 7; ++i) {
      float sum = r7[i];
      #pragma unroll
      for (int k = 0; k < 7; ++k) if (k < i) sum -= C[i][k] * y[k];
      y[i] = sum / C[i][i];
    }
    float x[7];
    #pragma unroll
    for (int i = 6; i >= 0; --i) {
      float sum = y[i];
      #pragma unroll
      for (int k = 0; k < 7; ++k) if (k > i) sum -= C[k][i] * x[k];
      x[i] = sum / C[i][i];
    }
    #pragma unroll
    for (int i = 0; i < 7; ++i) out[(s0 + ml)*7 + i] = x[i];
  }
}

extern "C" void kernel_launch(void* const* d_in, const int* in_sizes, int n_in,
                              void* d_out, int out_size, void* d_ws, size_t ws_size,
                              hipStream_t stream) {
  (void)in_sizes; (void)n_in; (void)out_size; (void)ws_size;
  const float* q   = (const float*)d_in[0];
  const float* qd  = (const float*)d_in[1];
  const float* mW0 = (const float*)d_in[2];  const float* mb0 = (const float*)d_in[3];
  const float* mW1 = (const float*)d_in[4];  const float* mb1 = (const float*)d_in[5];
  const float* mW2 = (const float*)d_in[6];  const float* mb2 = (const float*)d_in[7];
  const float* mW3 = (const float*)d_in[8];  const float* mb3 = (const float*)d_in[9];
  const float* pW0 = (const float*)d_in[10]; const float* pb0 = (const float*)d_in[11];
  const float* pW1 = (const float*)d_in[12]; const float* pb1 = (const float*)d_in[13];
  const float* pW2 = (const float*)d_in[14]; const float* pb2 = (const float*)d_in[15];
  const float* pW3 = (const float*)d_in[16]; const float* pb3 = (const float*)d_in[17];
  const float* fW0 = (const float*)d_in[18]; const float* fb0 = (const float*)d_in[19];
  const float* fW1 = (const float*)d_in[20]; const float* fb1 = (const float*)d_in[21];
  const float* fW2 = (const float*)d_in[22]; const float* fb2 = (const float*)d_in[23];
  const float* fW3 = (const float*)d_in[24]; const float* fb3 = (const float*)d_in[25];
  float* out = (float*)d_out;
  u16* ws = (u16*)d_ws;

  pack_kernel<<<dim3((TOTF16 + 255)/256), dim3(256), 0, stream>>>(
      mW0, mb0, mW1, mW2, mW3, pW0, pb0, pW1, pW2, pW3, fW0, fb0, fW1, fW2, fW3, ws);

  delan_kernel<<<dim3(NBLK), dim3(NT), 0, stream>>>(
      q, qd, mb1, mb2, mb3, pb1, pb2, pb3, fb1, fb2, fb3,
      (const char*)ws, out);
}

// Round 10
// 109.926 us; speedup vs baseline: 1.1255x; 1.1255x over previous
//
#include <hip/hip_runtime.h>

#define NT 512
#define TM 32
#define NBLK (65536/TM)

typedef unsigned int u32;
typedef unsigned short u16;
typedef __attribute__((ext_vector_type(4))) float f32x4;
typedef __attribute__((ext_vector_type(8))) _Float16 f16x8;
typedef __attribute__((ext_vector_type(4))) _Float16 f16x4;
typedef __attribute__((ext_vector_type(2))) __fp16 fp16x2r;   // cvt_pkrtz return type

namespace {
constexpr int TI_[28] = {0,1,1,2,2,2,3,3,3,3,4,4,4,4,4,5,5,5,5,5,5,6,6,6,6,6,6,6};
constexpr int TJ_[28] = {0,0,1,0,1,2,0,1,2,3,0,1,2,3,4,0,1,2,3,4,5,0,1,2,3,4,5,6};
constexpr bool DG_[28] = {1,0,1,0,0,1,0,0,0,1,0,0,0,0,1,0,0,0,0,0,1,0,0,0,0,0,0,1};

// 19 weight images in ws, byte offsets. Per image: [hi plane][lo plane],
// each plane = [K/8 slots][N][8 f16].  (unchanged)
constexpr int IB[20] = {0,16384,81920,147456,163840,180224,245760,311296,319488,
                        335872,401408,466944,475136,540672,606208,614400,630784,
                        696320,761856,778240};
constexpr int IN_[19]  = {128,128,128,32,128,128,128,16,128,128,128,16,128,128,16,128,128,128,32};
constexpr int ITY_[19] = {0,1,1,2,3,4,4,5,0,1,1,6,4,4,5,0,1,1,2};
constexpr int TOTF16 = 778240/2;
}

__device__ __forceinline__ float sp_f(float z) {
  float t = exp2f(-fabsf(z)*1.44269504f);
  return fmaxf(z, 0.f) + 0.69314718f*__log2f(1.f + t);
}
__device__ __forceinline__ float sigm_f(float z) {
  float t = exp2f(-z*1.44269504f);
  return __builtin_amdgcn_rcpf(1.f + t);
}
__device__ __forceinline__ float sig_a(float a) {  // sigmoid(z) from a=softplus(z)
  return 1.f - exp2f(-a*1.44269504f);
}

__device__ __forceinline__ u16 h2b(_Float16 h) { union{_Float16 f; u16 u;} c; c.f = h; return c.u; }
__device__ __forceinline__ u16 f16b(float x)   { return h2b((_Float16)x); }
__device__ __forceinline__ float b2f(u16 b)    { union{u16 u; _Float16 f;} c; c.u = b; return (float)c.f; }
__device__ __forceinline__ f16x8 fz8()         { return (f16x8)(_Float16)0.f; }

// 4x f32 -> f16x4 via 2x v_cvt_pkrtz (RTZ rounding, fine at our margins)
__device__ __forceinline__ f16x4 pk4(f32x4 v) {
  union { struct { fp16x2r a, b; } p; f16x4 v; } u;
  u.p.a = __builtin_amdgcn_cvt_pkrtz(v[0], v[1]);
  u.p.b = __builtin_amdgcn_cvt_pkrtz(v[2], v[3]);
  return u.v;
}

__device__ __forceinline__ f32x4 mm(f16x8 a, f16x8 b, f32x4 c) {
  return __builtin_amdgcn_mfma_f32_16x16x32_f16(a, b, c, 0, 0, 0);
}

// ---- f16 plane [32 m][128 n], 16 slots/row of 16B, slot XOR (row&7) ----
__device__ __forceinline__ f16x8 aread(const u16* P, int row, int s) {
  return *(const f16x8*)(P + row*128 + ((s ^ (row & 7)) << 3));
}
__device__ __forceinline__ int aidx4(int mrow, int n2) {
  return mrow*128 + (((n2 >> 3) ^ (mrow & 7)) << 3) + (n2 & 7);
}
__device__ __forceinline__ void awrite4(u16* P, int mrow, int n2, f16x4 v) {
  *(f16x4*)(P + aidx4(mrow, n2)) = v;
}
__device__ __forceinline__ f16x4 aread4(const u16* P, int mrow, int n2) {
  return *(const f16x4*)(P + aidx4(mrow, n2));
}
// ---- [32][8] q-matrix plane: only k-group 0 real, others zero ----
__device__ __forceinline__ f16x8 aq8(const u16* P, int row, int g) {
  f16x8 v = *(const f16x8*)(P + row*8);
  return g ? fz8() : v;
}
// ---- [32][32] ub plane: 4 slots, XOR (row&3) ----
__device__ __forceinline__ f16x8 ubread(const u16* P, int row, int g) {
  return *(const f16x8*)(P + row*32 + ((g ^ (row & 3)) << 3));
}
// ---- weight fragment (A operand) from global image plane ----
__device__ __forceinline__ f16x8 bread(const char* img, int N, int sk, int n) {
  return *(const f16x8*)(img + ((sk*N + n) << 4));
}

struct __align__(16) Smem {
  u16 mh1[4096], mh2[4096], mh3[4096];   // mass/pot act hi (sigma sources, reused)
  u16 X[4096], Y[4096];                  // lo ping-pong / grad / jvp / fric ping-pong
  u16 qmh[256], qml[256], qdb[256];      // [32][8]
  u16 ub[1024];                          // [32][32] cotangent; later aliased as cfH [28][32]
  float cTm[896];                        // c then vals, plain [28][32]
  u16 dcH[896];                          // [28][32] plain f16
  float GQ1[256], GQp[256];              // [32][8]
  float V[32];
};
static_assert(sizeof(Smem) <= 53248, "need 3 blocks/CU incl. alloc granule");

// ---------- fwd hi/lo: D = W^T X^T, TC n2-tiles {tile0 + j*tstep} ----------
template<int KS, bool QSRC, int TC>
__device__ __forceinline__ void fwd_hl(const u16* Bh, const u16* Bl, u16* Oh, u16* Ol,
                                       const char* img, int hb, const float* bias,
                                       int tile0, int tstep, int l) {
  const int m = l & 15, g = l >> 4;
  f32x4 H[TC][2], X[TC][2];
  #pragma unroll
  for (int j=0;j<TC;++j)
    #pragma unroll
    for (int mt=0;mt<2;++mt) { H[j][mt]=(f32x4){0,0,0,0}; X[j][mt]=(f32x4){0,0,0,0}; }
  __builtin_amdgcn_s_setprio(1);
  #pragma unroll
  for (int ks=0; ks<KS; ++ks) {
    const int sk = ks*4 + g;
    f16x8 bh[2], bl[2];
    #pragma unroll
    for (int mt=0;mt<2;++mt) {
      const int row = mt*16+m;
      bh[mt] = QSRC ? aq8(Bh,row,g) : aread(Bh,row,sk);
      bl[mt] = QSRC ? aq8(Bl,row,g) : aread(Bl,row,sk);
    }
    #pragma unroll
    for (int j=0;j<TC;++j) {
      const int n = (tile0 + j*tstep)*16 + m;
      const f16x8 wh = bread(img,128,sk,n);
      const f16x8 wl = bread(img+hb,128,sk,n);
      #pragma unroll
      for (int mt=0;mt<2;++mt) {
        H[j][mt]=mm(wh,bh[mt],H[j][mt]);
        X[j][mt]=mm(wl,bh[mt],X[j][mt]);
        X[j][mt]=mm(wh,bl[mt],X[j][mt]);
      }
    }
  }
  __builtin_amdgcn_s_setprio(0);
  #pragma unroll
  for (int j=0;j<TC;++j) {
    const int n2 = (tile0 + j*tstep)*16 + 4*g;
    f32x4 bv = bias ? *(const f32x4*)(bias + n2) : (f32x4){0,0,0,0};
    #pragma unroll
    for (int mt=0;mt<2;++mt) {
      const int mrow = mt*16 + m;
      f16x4 vh, vl;
      #pragma unroll
      for (int r=0;r<4;++r) {
        const float o = sp_f(H[j][mt][r] + X[j][mt][r]*(1.f/4096.f) + bv[r]);
        const _Float16 hh = (_Float16)o;
        vh[r] = hh;
        vl[r] = (_Float16)((o - (float)hh)*4096.f);
      }
      awrite4(Oh, mrow, n2, vh);
      awrite4(Ol, mrow, n2, vl);
    }
  }
}

// ---------- fwd hi-only: TC n2-tiles ----------
template<int KS, bool QSRC, int TC>
__device__ __forceinline__ void fwd_h(const u16* Bh, u16* Oh, const char* img,
                                      const float* bias, int tile0, int tstep, int l) {
  const int m = l & 15, g = l >> 4;
  f32x4 H[TC][2];
  #pragma unroll
  for (int j=0;j<TC;++j)
    #pragma unroll
    for (int mt=0;mt<2;++mt) H[j][mt]=(f32x4){0,0,0,0};
  __builtin_amdgcn_s_setprio(1);
  #pragma unroll
  for (int ks=0; ks<KS; ++ks) {
    const int sk = ks*4 + g;
    f16x8 bh[2];
    #pragma unroll
    for (int mt=0;mt<2;++mt) {
      const int row = mt*16+m;
      bh[mt] = QSRC ? aq8(Bh,row,g) : aread(Bh,row,sk);
    }
    #pragma unroll
    for (int j=0;j<TC;++j) {
      const f16x8 wh = bread(img,128,sk,(tile0 + j*tstep)*16+m);
      #pragma unroll
      for (int mt=0;mt<2;++mt) H[j][mt]=mm(wh,bh[mt],H[j][mt]);
    }
  }
  __builtin_amdgcn_s_setprio(0);
  #pragma unroll
  for (int j=0;j<TC;++j) {
    const int n2 = (tile0 + j*tstep)*16 + 4*g;
    f32x4 bv = bias ? *(const f32x4*)(bias + n2) : (f32x4){0,0,0,0};
    #pragma unroll
    for (int mt=0;mt<2;++mt) {
      const int mrow = mt*16 + m;
      f32x4 o;
      #pragma unroll
      for (int r=0;r<4;++r) o[r] = sp_f(H[j][mt][r] + bv[r]);
      awrite4(Oh, mrow, n2, pk4(o));
    }
  }
}

// ---------- grad K=128: out = sig_a(Sig) .* (W^T X^T) ----------
template<int TC>
__device__ __forceinline__ void grad128(const u16* Bin, const u16* Sig, u16* Out,
                                        const char* img, int tile0, int tstep, int l) {
  const int m = l & 15, g = l >> 4;
  f32x4 acc[TC][2];
  #pragma unroll
  for (int j=0;j<TC;++j)
    #pragma unroll
    for (int mt=0;mt<2;++mt) acc[j][mt]=(f32x4){0,0,0,0};
  __builtin_amdgcn_s_setprio(1);
  #pragma unroll
  for (int ks=0; ks<4; ++ks) {
    const int sk = ks*4 + g;
    f16x8 bh[2];
    #pragma unroll
    for (int mt=0;mt<2;++mt) bh[mt] = aread(Bin, mt*16+m, sk);
    #pragma unroll
    for (int j=0;j<TC;++j) {
      const f16x8 wh = bread(img,128,sk,(tile0 + j*tstep)*16+m);
      #pragma unroll
      for (int mt=0;mt<2;++mt) acc[j][mt]=mm(wh,bh[mt],acc[j][mt]);
    }
  }
  __builtin_amdgcn_s_setprio(0);
  #pragma unroll
  for (int j=0;j<TC;++j) {
    const int n2 = (tile0 + j*tstep)*16 + 4*g;
    #pragma unroll
    for (int mt=0;mt<2;++mt) {
      const int mrow = mt*16 + m;
      const f16x4 sg = aread4(Sig, mrow, n2);
      f32x4 o;
      #pragma unroll
      for (int r=0;r<4;++r) o[r] = sig_a((float)sg[r]) * acc[j][mt][r];
      awrite4(Out, mrow, n2, pk4(o));
    }
  }
}

// ---------- grad K=32: B from ub (ASRC=0) or q8 (ASRC=1) ----------
template<int ASRC, int TC>
__device__ __forceinline__ void grad32(const u16* Bin, const u16* Sig, u16* Out,
                                       const char* img, int tile0, int tstep, int l) {
  const int m = l & 15, g = l >> 4;
  f32x4 acc[TC][2];
  #pragma unroll
  for (int j=0;j<TC;++j)
    #pragma unroll
    for (int mt=0;mt<2;++mt) acc[j][mt]=(f32x4){0,0,0,0};
  __builtin_amdgcn_s_setprio(1);
  {
    f16x8 bh[2];
    #pragma unroll
    for (int mt=0;mt<2;++mt) {
      const int row = mt*16+m;
      bh[mt] = (ASRC==0) ? ubread(Bin,row,g) : aq8(Bin,row,g);
    }
    #pragma unroll
    for (int j=0;j<TC;++j) {
      const f16x8 wh = bread(img,128,g,(tile0 + j*tstep)*16+m);
      #pragma unroll
      for (int mt=0;mt<2;++mt) acc[j][mt]=mm(wh,bh[mt],acc[j][mt]);
    }
  }
  __builtin_amdgcn_s_setprio(0);
  #pragma unroll
  for (int j=0;j<TC;++j) {
    const int n2 = (tile0 + j*tstep)*16 + 4*g;
    #pragma unroll
    for (int mt=0;mt<2;++mt) {
      const int mrow = mt*16 + m;
      const f16x4 sg = aread4(Sig, mrow, n2);
      f32x4 o;
      #pragma unroll
      for (int r=0;r<4;++r) o[r] = sig_a((float)sg[r]) * acc[j][mt][r];
      awrite4(Out, mrow, n2, pk4(o));
    }
  }
}

// ---------- G2p: B = up[m]*sigma(a3p) on the fly; image pre-scaled by W3p ----------
template<int TC>
__device__ __forceinline__ void gradPotF(const u16* A3p, const float* V, float pb3v,
                                         const u16* Sig, u16* Out, const char* img,
                                         int tile0, int tstep, int l) {
  const int m = l & 15, g = l >> 4;
  float up[2];
  #pragma unroll
  for (int mt=0;mt<2;++mt) up[mt] = sigm_f(V[mt*16+m] + pb3v);
  f32x4 acc[TC][2];
  #pragma unroll
  for (int j=0;j<TC;++j)
    #pragma unroll
    for (int mt=0;mt<2;++mt) acc[j][mt]=(f32x4){0,0,0,0};
  #pragma unroll
  for (int ks=0; ks<4; ++ks) {
    const int sk = ks*4 + g;
    f16x8 bh[2];
    #pragma unroll
    for (int mt=0;mt<2;++mt) {
      const f16x8 a3 = aread(A3p, mt*16+m, sk);
      f16x8 t;
      #pragma unroll
      for (int e=0;e<8;++e) t[e] = (_Float16)(up[mt]*sig_a((float)a3[e]));
      bh[mt] = t;
    }
    #pragma unroll
    for (int j=0;j<TC;++j) {
      const f16x8 wh = bread(img,128,sk,(tile0 + j*tstep)*16+m);
      #pragma unroll
      for (int mt=0;mt<2;++mt) acc[j][mt]=mm(wh,bh[mt],acc[j][mt]);
    }
  }
  #pragma unroll
  for (int j=0;j<TC;++j) {
    const int n2 = (tile0 + j*tstep)*16 + 4*g;
    #pragma unroll
    for (int mt=0;mt<2;++mt) {
      const int mrow = mt*16 + m;
      const f16x4 sg = aread4(Sig, mrow, n2);
      f32x4 o;
      #pragma unroll
      for (int r=0;r<4;++r) o[r] = sig_a((float)sg[r]) * acc[j][mt][r];
      awrite4(Out, mrow, n2, pk4(o));
    }
  }
}

// ---------- l3 (28 outputs): 4 waves wg 0-3: n2t = wg&1, mt = wg>>1 ----------
template<bool HL>
__device__ __forceinline__ void l3(const u16* Bh, const u16* Bl, const char* img, int hb,
                                   const float* b3, float* cT, u16* cH, int wg, int l) {
  const int m = l & 15, g = l >> 4;
  const int n2t = wg & 1, mt = wg >> 1;
  const int mrow = mt*16 + m;
  f32x4 H = {0,0,0,0}, X = {0,0,0,0};
  __builtin_amdgcn_s_setprio(1);
  #pragma unroll
  for (int ks=0; ks<4; ++ks) {
    const int sk = ks*4 + g;
    const f16x8 bh = aread(Bh, mrow, sk);
    const f16x8 wh = bread(img,32,sk, n2t*16+m);
    H = mm(wh, bh, H);
    if (HL) {
      const f16x8 wl = bread(img+hb,32,sk, n2t*16+m);
      const f16x8 bl = aread(Bl, mrow, sk);
      X = mm(wl, bh, X);
      X = mm(wh, bl, X);
    }
  }
  __builtin_amdgcn_s_setprio(0);
  const int u0 = n2t*16 + 4*g;
  if (u0 < 28) {
    f32x4 bv = b3 ? *(const f32x4*)(b3 + u0) : (f32x4){0,0,0,0};
    #pragma unroll
    for (int r=0;r<4;++r) {
      const float v = H[r] + (HL ? X[r]*(1.f/4096.f) : 0.f) + bv[r];
      if (HL) cT[(u0+r)*32 + mrow] = v;
      else    cH[(u0+r)*32 + mrow] = f16b(v);
    }
  }
}

// ---------- n16: head (-> V) or gq (-> GQ[32][8]); 2 waves mt 0-1 ----------
template<bool HEAD>
__device__ __forceinline__ void n16(const u16* Bin, const char* img,
                                    float* GQ, float* V, int mt, int l) {
  const int m = l & 15, g = l >> 4;
  const int mrow = mt*16 + m;
  f32x4 acc = {0,0,0,0};
  #pragma unroll
  for (int ks=0; ks<4; ++ks) {
    const int sk = ks*4 + g;
    const f16x8 bh = aread(Bin, mrow, sk);
    const f16x8 wh = bread(img,16,sk,m);
    acc = mm(wh, bh, acc);
  }
  if (HEAD) {
    if (g == 0) V[mrow] = acc[0];
  } else {
    if (g < 2) {
      #pragma unroll
      for (int r=0;r<4;++r) GQ[mrow*8 + 4*g + r] = acc[r];
    }
  }
}

// ================= pack kernel (unchanged) =================
__global__ __launch_bounds__(256)
void pack_kernel(const float* __restrict__ mW0, const float* __restrict__ mb0,
                 const float* __restrict__ mW1, const float* __restrict__ mW2,
                 const float* __restrict__ mW3,
                 const float* __restrict__ pW0, const float* __restrict__ pb0,
                 const float* __restrict__ pW1, const float* __restrict__ pW2,
                 const float* __restrict__ pW3,
                 const float* __restrict__ fW0, const float* __restrict__ fb0,
                 const float* __restrict__ fW1, const float* __restrict__ fW2,
                 const float* __restrict__ fW3,
                 u16* __restrict__ ws)
{
  const int idx = blockIdx.x*256 + threadIdx.x;
  if (idx >= TOTF16) return;
  int img = 0;
  #pragma unroll
  for (int i = 1; i < 19; ++i) if (idx >= IB[i]/2) img = i;
  const int rem = idx - IB[img]/2;
  const int N = IN_[img];
  const int psz = (IB[img+1] - IB[img]) / 4;   // f16 per plane = K*N
  const int plane = rem >= psz;
  const int e = plane ? rem - psz : rem;
  const int slot = e / (N*8);
  const int r1 = e - slot*(N*8);
  const int n = r1 >> 3, ee = r1 & 7;
  const int k = slot*8 + ee;

  const float* W = nullptr; const float* B = nullptr;
  switch (img) {
    case 0:  W = mW0; B = mb0; break;
    case 1:  W = mW1; break;   case 2:  W = mW2; break;
    case 3:  W = mW3; break;   case 4:  W = mW3; break;
    case 5:  W = mW2; break;   case 6:  W = mW1; break;
    case 7:  W = mW0; break;
    case 8:  W = pW0; B = pb0; break;
    case 9:  W = pW1; break;   case 10: W = pW2; break;
    case 11: W = pW3; break;   case 12: W = pW2; break;
    case 13: W = pW1; break;   case 14: W = pW0; break;
    case 15: W = fW0; B = fb0; break;
    case 16: W = fW1; break;   case 17: W = fW2; break;
    default: W = fW3; break;
  }
  float v = 0.f;
  switch (ITY_[img]) {
    case 0: v = (k < 7) ? W[k*128 + n] : (k == 7 ? B[n] : 0.f); break;
    case 1: v = W[k*128 + n]; break;
    case 2: v = (n < 28) ? W[k*28 + n] : 0.f; break;
    case 3: v = (k < 28) ? W[n*28 + k] : 0.f; break;
    case 4: v = W[n*128 + k]; break;
    case 5: v = (n < 7) ? W[n*128 + k] : 0.f; break;
    default: v = (n == 0) ? W[k] : 0.f; break;
  }
  if (img == 12) v *= pW3[k];   // fold diag(W3p) into G2p's image
  const _Float16 h = (_Float16)v;
  union { _Float16 f; u16 u; } c;
  c.f = plane ? (_Float16)((v - (float)h) * 4096.f) : h;
  ws[idx] = c.u;
}

// ================= main kernel =================
__global__ __launch_bounds__(NT, 6)
void delan_kernel(const float* __restrict__ qg, const float* __restrict__ qdg,
    const float* __restrict__ mb1, const float* __restrict__ mb2, const float* __restrict__ mb3,
    const float* __restrict__ pb1, const float* __restrict__ pb2, const float* __restrict__ pb3,
    const float* __restrict__ fb1, const float* __restrict__ fb2, const float* __restrict__ fb3,
    const char* __restrict__ ws, float* __restrict__ out)
{
  __shared__ Smem S;
  const int t = threadIdx.x;
  const int l = t & 63;
  const int w = __builtin_amdgcn_readfirstlane(t >> 6);
  const int wg = w & 3;
  const int s0 = blockIdx.x * TM;
  u16* const cfH = S.ub;   // alias: ub dead after ph7, cfH born ph14 (1792 <= 2048 B)

  // ---- ph0: build q / qd matrices ----
  if (t < 256) {
    const int m = t >> 3, c = t & 7;
    const float v = (c < 7) ? qg[(s0 + m)*7 + c] : 1.f;   // col 7 = 1.0 bias hook
    const _Float16 hh = (_Float16)v;
    S.qmh[t] = h2b(hh);
    S.qml[t] = f16b((v - (float)hh)*4096.f);
  } else {
    const int idx = t - 256;
    const int m = idx >> 3, c = idx & 7;
    S.qdb[idx] = (c < 7) ? f16b(qdg[(s0 + m)*7 + c]) : (u16)0;
  }
  __syncthreads();

  // ph1: L0m -> mh1 + X(lo1)
  fwd_hl<1,true,1>(S.qmh, S.qml, S.mh1, S.X, ws+IB[0], (IB[1]-IB[0])/2, nullptr, w, 1, l);
  __syncthreads();
  // ph2: L1m -> mh2 + Y(lo2)
  fwd_hl<4,false,1>(S.mh1, S.X, S.mh2, S.Y, ws+IB[1], (IB[2]-IB[1])/2, mb1, w, 1, l);
  __syncthreads();
  // ph3: L2m -> mh3 + X(lo3)
  fwd_hl<4,false,1>(S.mh2, S.Y, S.mh3, S.X, ws+IB[2], (IB[3]-IB[2])/2, mb2, w, 1, l);
  __syncthreads();
  // ph4: l3m (w0-3) | d1 -> Y (w4-7)
  if (w < 4) l3<true>(S.mh3, S.X, ws+IB[3], (IB[4]-IB[3])/2, mb3, S.cTm, nullptr, wg, l);
  else       grad32<1,2>(S.qdb, S.mh1, S.Y, ws+IB[0], wg, 4, l);
  __syncthreads();
  // ph5: P1 (w0) | d2: Y -> X (w4-7)
  if (w == 0 && l < 32) {
    const int ml = l;
    float qdv[7];
    #pragma unroll
    for (int i = 0; i < 7; ++i) qdv[i] = qdg[(s0 + ml)*7 + i];
    float vals[28], wvv[7] = {0,0,0,0,0,0,0};
    #pragma unroll
    for (int u = 0; u < 28; ++u) {
      const float cv = S.cTm[u*32 + ml];
      vals[u] = DG_[u] ? __expf(cv) : cv;
    }
    #pragma unroll
    for (int u = 0; u < 28; ++u) wvv[TJ_[u]] = fmaf(vals[u], qdv[TI_[u]], wvv[TJ_[u]]);
    #pragma unroll
    for (int u = 0; u < 28; ++u) S.cTm[u*32 + ml] = vals[u];   // c -> vals in place
    #pragma unroll
    for (int u = 0; u < 28; ++u) {
      const float uval = (DG_[u] ? vals[u] : 1.f) * qdv[TI_[u]] * wvv[TJ_[u]];
      S.ub[ml*32 + (((u >> 3) ^ (ml & 3)) << 3) + (u & 7)] = f16b(uval);
    }
    #pragma unroll
    for (int u = 28; u < 32; ++u)
      S.ub[ml*32 + (((u >> 3) ^ (ml & 3)) << 3) + (u & 7)] = 0;
  } else if (w >= 4) {
    grad128<2>(S.Y, S.mh2, S.X, ws+IB[1], wg, 4, l);
  }
  __syncthreads();
  // ph6: d3: X -> Y (8 waves)
  grad128<1>(S.X, S.mh3, S.Y, ws+IB[2], w, 1, l);
  __syncthreads();
  // ph7: dc = l3(Y) (w0-3) | G3: ub -> X (w4-7)
  if (w < 4) l3<false>(S.Y, nullptr, ws+IB[3], 0, nullptr, nullptr, S.dcH, wg, l);
  else       grad32<0,2>(S.ub, S.mh3, S.X, ws+IB[4], wg, 4, l);
  __syncthreads();
  // ph8: G2: X -> Y (8 waves)
  grad128<1>(S.X, S.mh2, S.Y, ws+IB[5], w, 1, l);
  __syncthreads();
  // ph9: G1: Y -> X (8 waves)
  grad128<1>(S.Y, S.mh1, S.X, ws+IB[6], w, 1, l);
  __syncthreads();
  // ph10: gq = n16(X) (w0-1) | L0p -> mh1 (w4-7)
  if (w < 2)       n16<false>(S.X, ws+IB[7], S.GQ1, nullptr, w, l);
  else if (w >= 4) fwd_h<1,true,2>(S.qmh, S.mh1, ws+IB[8], nullptr, wg, 4, l);
  __syncthreads();
  // ph11: L1p: mh1 -> mh2 (w0-3) | L0f -> Y (w4-7)
  if (w < 4) fwd_h<4,false,2>(S.mh1, S.mh2, ws+IB[9], pb1, wg, 4, l);
  else       fwd_h<1,true,2>(S.qmh, S.Y, ws+IB[15], nullptr, wg, 4, l);
  __syncthreads();
  // ph12: L2p: mh2 -> mh3 (w0-3) | L1f: Y -> X (w4-7)
  if (w < 4) fwd_h<4,false,2>(S.mh2, S.mh3, ws+IB[10], pb2, wg, 4, l);
  else       fwd_h<4,false,2>(S.Y, S.X, ws+IB[16], fb1, wg, 4, l);
  __syncthreads();
  // ph13: head = n16(mh3) (w0-1) | L2f: X -> Y (w4-7)
  if (w < 2)       n16<true>(S.mh3, ws+IB[11], nullptr, S.V, w, l);
  else if (w >= 4) fwd_h<4,false,2>(S.X, S.Y, ws+IB[17], fb2, wg, 4, l);
  __syncthreads();
  // ph14: G2p in-place mh2 (w0-3) | l3f(Y) -> cfH (w4-7)
  if (w < 4) gradPotF<2>(S.mh3, S.V, pb3[0], S.mh2, S.mh2, ws+IB[12], wg, 4, l);
  else       l3<false>(S.Y, nullptr, ws+IB[18], 0, fb3, nullptr, cfH, wg, l);
  __syncthreads();
  // ph15: G1p: mh2 -> X (8 waves)
  grad128<1>(S.mh2, S.mh1, S.X, ws+IB[13], w, 1, l);
  __syncthreads();
  // ph16: gqp = n16(X) (w0-1)
  if (w < 2) n16<false>(S.X, ws+IB[14], S.GQp, nullptr, w, l);
  __syncthreads();

  // ph17: P2 + P3 (wave 0, lanes 0-31)
  if (w == 0 && l < 32) {
    const int ml = l;
    float qdv[7];
    #pragma unroll
    for (int i = 0; i < 7; ++i) qdv[i] = qdg[(s0 + ml)*7 + i];
    float lv[28];
    #pragma unroll
    for (int u = 0; u < 28; ++u) lv[u] = S.cTm[u*32 + ml];
    float wvv[7] = {0,0,0,0,0,0,0};
    #pragma unroll
    for (int u = 0; u < 28; ++u) wvv[TJ_[u]] = fmaf(lv[u], qdv[TI_[u]], wvv[TJ_[u]]);
    float cor[7] = {0,0,0,0,0,0,0}, t2[7] = {0,0,0,0,0,0,0};
    #pragma unroll
    for (int u = 0; u < 28; ++u) {
      const float dv = (DG_[u] ? lv[u] : 1.f) * b2f(S.dcH[u*32 + ml]);
      cor[TI_[u]] = fmaf(dv, wvv[TJ_[u]], cor[TI_[u]]);
      t2[TJ_[u]]  = fmaf(dv, qdv[TI_[u]], t2[TJ_[u]]);
    }
    #pragma unroll
    for (int u = 0; u < 28; ++u) cor[TI_[u]] = fmaf(lv[u], t2[TJ_[u]], cor[TI_[u]]);
    float r7[7];
    #pragma unroll
    for (int i = 0; i < 7; ++i)
      r7[i] = S.GQ1[ml*8 + i] - cor[i] - S.GQp[ml*8 + i] - 1e-3f*qdv[i];
    // friction
    float fv[28];
    #pragma unroll
    for (int u = 0; u < 28; ++u) {
      const float cv = b2f(cfH[u*32 + ml]);
      fv[u] = DG_[u] ? __expf(cv) : cv;
    }
    float wf[7] = {0,0,0,0,0,0,0};
    #pragma unroll
    for (int u = 0; u < 28; ++u) wf[TJ_[u]] = fmaf(fv[u], qdv[TI_[u]], wf[TJ_[u]]);
    #pragma unroll
    for (int u = 0; u < 28; ++u) r7[TI_[u]] -= fv[u]*wf[TJ_[u]];

    float L[7][7];
    #pragma unroll
    for (int i = 0; i < 7; ++i)
      #pragma unroll
      for (int j = 0; j < 7; ++j) L[i][j] = 0.f;
    #pragma unroll
    for (int u = 0; u < 28; ++u) L[TI_[u]][TJ_[u]] = lv[u];

    float M[7][7];
    #pragma unroll
    for (int i = 0; i < 7; ++i)
      #pragma unroll
      for (int j = 0; j < 7; ++j)
        if (j <= i) {
          float sum = (i == j) ? 1.1e-3f : 0.f;
          #pragma unroll
          for (int k = 0; k < 7; ++k) if (k <= j) sum = fmaf(L[i][k], L[j][k], sum);
          M[i][j] = sum;
        }
    float C[7][7];
    #pragma unroll
    for (int i = 0; i < 7; ++i)
      #pragma unroll
      for (int j = 0; j < 7; ++j)
        if (j <= i) {
          float sum = M[i][j];
          #pragma unroll
          for (int k = 0; k < 7; ++k) if (k < j) sum -= C[i][k] * C[j][k];
          if (j == i) C[i][j] = sqrtf(fmaxf(sum, 1e-12f));
          else        C[i][j] = sum / C[j][j];
        }
    float y[7];
    #pragma unroll
    for (int i = 0; i < 7; ++i) {
      float sum = r7[i];
      #pragma unroll
      for (int k = 0; k < 7; ++k) if (k < i) sum -= C[i][k] * y[k];
      y[i] = sum / C[i][i];
    }
    float x[7];
    #pragma unroll
    for (int i = 6; i >= 0; --i) {
      float sum = y[i];
      #pragma unroll
      for (int k = 0; k < 7; ++k) if (k > i) sum -= C[k][i] * x[k];
      x[i] = sum / C[i][i];
    }
    #pragma unroll
    for (int i = 0; i < 7; ++i) out[(s0 + ml)*7 + i] = x[i];
  }
}

extern "C" void kernel_launch(void* const* d_in, const int* in_sizes, int n_in,
                              void* d_out, int out_size, void* d_ws, size_t ws_size,
                              hipStream_t stream) {
  (void)in_sizes; (void)n_in; (void)out_size; (void)ws_size;
  const float* q   = (const float*)d_in[0];
  const float* qd  = (const float*)d_in[1];
  const float* mW0 = (const float*)d_in[2];  const float* mb0 = (const float*)d_in[3];
  const float* mW1 = (const float*)d_in[4];  const float* mb1 = (const float*)d_in[5];
  const float* mW2 = (const float*)d_in[6];  const float* mb2 = (const float*)d_in[7];
  const float* mW3 = (const float*)d_in[8];  const float* mb3 = (const float*)d_in[9];
  const float* pW0 = (const float*)d_in[10]; const float* pb0 = (const float*)d_in[11];
  const float* pW1 = (const float*)d_in[12]; const float* pb1 = (const float*)d_in[13];
  const float* pW2 = (const float*)d_in[14]; const float* pb2 = (const float*)d_in[15];
  const float* pW3 = (const float*)d_in[16]; const float* pb3 = (const float*)d_in[17];
  const float* fW0 = (const float*)d_in[18]; const float* fb0 = (const float*)d_in[19];
  const float* fW1 = (const float*)d_in[20]; const float* fb1 = (const float*)d_in[21];
  const float* fW2 = (const float*)d_in[22]; const float* fb2 = (const float*)d_in[23];
  const float* fW3 = (const float*)d_in[24]; const float* fb3 = (const float*)d_in[25];
  float* out = (float*)d_out;
  u16* ws = (u16*)d_ws;

  pack_kernel<<<dim3((TOTF16 + 255)/256), dim3(256), 0, stream>>>(
      mW0, mb0, mW1, mW2, mW3, pW0, pb0, pW1, pW2, pW3, fW0, fb0, fW1, fW2, fW3, ws);

  delan_kernel<<<dim3(NBLK), dim3(NT), 0, stream>>>(
      q, qd, mb1, mb2, mb3, pb1, pb2, pb3, fb1, fb2, fb3,
      (const char*)ws, out);
}